// Round 8
// baseline (756.247 us; speedup 1.0000x reference)
//
#include <hip/hip_runtime.h>
#include <hip/hip_bf16.h>

typedef __hip_bfloat16 bf16;
typedef __attribute__((ext_vector_type(8))) short short8;
typedef __attribute__((ext_vector_type(4))) float floatx4;
typedef __attribute__((ext_vector_type(16))) float floatx16;

#define B_ 2
#define L_ 4096
#define D_ 1024
#define DI_ 2048
#define H_ 16
#define HD_ 128
#define N_ 128
#define CS_ 256
#define MC_ 256
#define NC_ 16
#define PROJ_ 8208

__device__ __forceinline__ float bf2f(short s) {
    return __uint_as_float(((unsigned)(unsigned short)s) << 16);
}
__device__ __forceinline__ short f2bf(float f) {
    __hip_bfloat16 h = __float2bfloat16(f);
    return *(short*)&h;
}

__device__ __forceinline__ void gl_lds16(const void* g, void* s) {
    __builtin_amdgcn_global_load_lds(
        (const __attribute__((address_space(1))) void*)g,
        (__attribute__((address_space(3))) void*)s, 16, 0, 0);
}

// ---------------------------------------------------------------------------
// Generic bf16 MFMA GEMM: C[M,N] = A[M,K] @ Bt[N,K]^T  (both row-major, K contig)
// 128x128 tile, 4 waves, 32x32x16 MFMA, global_load_lds(16B) staging,
// XCD-aware supertile remap, XOR LDS bank swizzle.
// tri: 0=none, 1=output causal-masked (skip fully-masked tiles, Sm),
//      2=A block-lower-triangular (K limited to m0+128, intra).
// ---------------------------------------------------------------------------
struct GemmP {
    const bf16* A; const bf16* Bt;
    float* C; bf16* CB; bf16* CB2; bf16* CB3;
    const float* add0; const float* add1; const bf16* add0b; const float* scr;
    long lda, ldb, ldc;
    int M, N, K, zinner, tri;
    long a_zo, a_zi, b_zo, b_zi, c_zo, c_zi;
};

template<int EPI>
__global__ __launch_bounds__(256, 2) void gemm_bt(GemmP p)
{
    // ---- XCD-aware tile remap (exact bijection grid -> tiles) ----
    int NT = gridDim.x, MT = gridDim.y;
    long T = (long)NT * MT * gridDim.z;
    long flat = ((long)blockIdx.z * MT + blockIdx.y) * NT + blockIdx.x;
    int xcd = (int)(flat & 7);
    long q = flat >> 3;
    long Tq = T >> 3; int Tr = (int)(T & 7);
    long tile = (long)xcd * Tq + (long)(xcd < Tr ? xcd : Tr) + q;
    long per_z = (long)NT * MT;
    int z = (int)(tile / per_z);
    int t2 = (int)(tile - (long)z * per_z);
    int FG = NT >> 3;
    int g, width, within;
    if (t2 < FG * MT * 8) { g = t2 / (MT * 8); width = 8; within = t2 - g * MT * 8; }
    else                  { g = FG; width = NT - FG * 8; within = t2 - FG * MT * 8; }
    int m_outer = within / (8 * width);
    int hb = MT - m_outer * 8; if (hb > 8) hb = 8;
    int inner = within - m_outer * 8 * width;
    int n_in = inner / hb, m_in = inner - n_in * hb;
    int m0 = (m_outer * 8 + m_in) * 128;
    int n0 = (g * 8 + n_in) * 128;

    int zo = z / p.zinner, zi = z % p.zinner;
    const bf16* A  = p.A  + (long)zo * p.a_zo + (long)zi * p.a_zi;
    const bf16* Bt = p.Bt + (long)zo * p.b_zo + (long)zi * p.b_zi;
    long coff = (long)zo * p.c_zo + (long)zi * p.c_zi;

    int tid = threadIdx.x;
    int lane = tid & 63, wave = tid >> 6;
    int wm = (wave >> 1) * 64, wn = (wave & 1) * 64;
    int ln31 = lane & 31, hi = lane >> 5;

    // fully-masked Sm tile: write zeros, skip compute
    if (p.tri == 1 && n0 >= m0 + 128) {
        if (EPI == 3) {
#pragma unroll
            for (int i = 0; i < 2; i++)
#pragma unroll
                for (int j = 0; j < 2; j++)
#pragma unroll
                    for (int r = 0; r < 16; r++) {
                        int gm = m0 + wm + i * 32 + (r & 3) + 8 * (r >> 2) + 4 * hi;
                        int gn = n0 + wn + j * 32 + ln31;
                        if (gm < p.M && gn < p.N)
                            p.CB[coff + (long)gm * p.ldc + gn] = __float2bfloat16(0.f);
                    }
        }
        return;
    }
    int Keff = (p.tri == 2) ? (m0 + 128 < p.K ? m0 + 128 : p.K) : p.K;

    __shared__ __align__(16) bf16 As[128 * 64];
    __shared__ __align__(16) bf16 Bs[128 * 64];

    floatx16 acc[2][2];
#pragma unroll
    for (int i = 0; i < 2; i++)
#pragma unroll
        for (int j = 0; j < 2; j++)
#pragma unroll
            for (int r = 0; r < 16; r++) acc[i][j][r] = 0.f;

    int lrow = lane >> 3;
    int lc = ((lane & 7) ^ lrow) * 8;     // XOR-swizzled column (write side)
    int wrow = wave * 32;
    int rx = lane & 7;                    // read-side xor key

    for (int k0 = 0; k0 < Keff; k0 += 64) {
#pragma unroll
        for (int t = 0; t < 4; t++) {
            int row = wrow + t * 8 + lrow;
            gl_lds16(A + (long)(m0 + row) * p.lda + k0 + lc, &As[(wrow + t * 8) * 64]);
            int bn = n0 + row; if (bn > p.N - 1) bn = p.N - 1;
            gl_lds16(Bt + (long)bn * p.ldb + k0 + lc, &Bs[(wrow + t * 8) * 64]);
        }
        __syncthreads();
#pragma unroll
        for (int ks = 0; ks < 64; ks += 16) {
            int lb = (ks >> 3) + hi;
            int po = ((lb ^ rx) << 3);
            short8 af[2], bq[2];
#pragma unroll
            for (int i = 0; i < 2; i++)
                af[i] = *(const short8*)&As[(wm + i * 32 + ln31) * 64 + po];
#pragma unroll
            for (int j = 0; j < 2; j++)
                bq[j] = *(const short8*)&Bs[(wn + j * 32 + ln31) * 64 + po];
#pragma unroll
            for (int i = 0; i < 2; i++)
#pragma unroll
                for (int j = 0; j < 2; j++)
                    acc[i][j] = __builtin_amdgcn_mfma_f32_32x32x16_bf16(af[i], bq[j], acc[i][j], 0, 0, 0);
        }
        __syncthreads();
    }

#pragma unroll
    for (int i = 0; i < 2; i++) {
#pragma unroll
        for (int j = 0; j < 2; j++) {
#pragma unroll
            for (int r = 0; r < 16; r++) {
                int gm = m0 + wm + i * 32 + (r & 3) + 8 * (r >> 2) + 4 * hi;
                int gn = n0 + wn + j * 32 + ln31;
                if (gm >= p.M || gn >= p.N) continue;
                float a = acc[i][j][r];
                if (EPI == 0) {
                    p.C[coff + (long)gm * p.ldc + gn] = a;
                } else if (EPI == 2) {                // proj 4-way split
                    if (gn < 2048)      p.CB [(long)gm * 2048 + gn]          = __float2bfloat16(a);
                    else if (gn < 4096) p.CB2[(long)gm * 2048 + (gn - 2048)] = __float2bfloat16(a);
                    else if (gn < 8192) p.CB3[(long)gm * 4096 + (gn - 4096)] = __float2bfloat16(a);
                    else                p.C  [(long)gm * 16   + (gn - 8192)] = a;
                } else if (EPI == 3) {                // Mmem causal decay mask -> bf16
                    float lg = p.scr[1];
                    float v = (gm > gn) ? a * __expf((float)(gm - 1 - gn) * lg) : 0.f;
                    p.CB[coff + (long)gm * p.ldc + gn] = __float2bfloat16(v);
                } else if (EPI == 4) {                // inter: acc*gp[m] + intra(bf16) -> bf16
                    long ix = coff + (long)gm * p.ldc + gn;
                    float t = a * p.scr[16 + gm] + __bfloat162float(p.add0b[ix]);
                    p.CB[ix] = __float2bfloat16(t);
                } else if (EPI == 6) {                // bf16 only
                    p.CB[coff + (long)gm * p.ldc + gn] = __float2bfloat16(a);
                } else if (EPI == 7) {                // final: x(f32) + out(bf16) + 0.5*acc
                    long ix = (long)gm * p.ldc + gn;
                    p.C[ix] = p.add0[ix] + __bfloat162float(p.add0b[ix]) + 0.5f * a;
                } else if (EPI == 8) {                // out_b + fused shift into wk
                    long ix = (long)gm * p.ldc + gn;
                    bf16 v = __float2bfloat16(a);
                    p.CB[ix] = v;
                    int l = gm & (L_ - 1);
                    if (l != L_ - 1) p.CB2[ix + p.ldc] = v;
                    if (l == 0) p.CB2[ix] = __float2bfloat16(0.f);
                }
            }
        }
    }
}

// ---------------------------------------------------------------------------
// Elementwise / helper kernels
// ---------------------------------------------------------------------------
__global__ void k_gamma(const float* decay, float* scr)
{
    int t = threadIdx.x;
    float g = 1.f / (1.f + expf(-decay[0]));
    float lg = logf(g);
    if (t == 0) { scr[0] = g; scr[1] = lg; scr[2] = expf(256.f * lg); }
    scr[16 + t]  = expf(lg * (float)t);          // gp
    scr[272 + t] = expf(lg * (float)(255 - t));  // gw
}

__global__ void k_f2ball(const float* __restrict__ s0, bf16* __restrict__ d0, long n0,
                         const float* __restrict__ s1, bf16* __restrict__ d1, long n1,
                         const float* __restrict__ s2, bf16* __restrict__ d2, long n2,
                         const float* __restrict__ s3, bf16* __restrict__ d3, long n3)
{
    long i = (long)blockIdx.x * 256 + threadIdx.x;
    const float* s; bf16* d; long rel = i;
    if (rel < n0) { s = s0; d = d0; }
    else { rel -= n0;
        if (rel < n1) { s = s1; d = d1; }
        else { rel -= n1;
            if (rel < n2) { s = s2; d = d2; }
            else { rel -= n2; if (rel >= n3) return; s = s3; d = d3; }
        }
    }
    float4 v = ((const float4*)s)[rel];
    bf16* o = d + rel * 4;
    o[0] = __float2bfloat16(v.x); o[1] = __float2bfloat16(v.y);
    o[2] = __float2bfloat16(v.z); o[3] = __float2bfloat16(v.w);
}

__global__ __launch_bounds__(256) void k_rmsnorm(const float* __restrict__ x,
                                                 const float* __restrict__ w,
                                                 bf16* __restrict__ o)
{
    int row = blockIdx.x, t = threadIdx.x;
    float4 xv = ((const float4*)(x + (long)row * D_))[t];
    float s = xv.x*xv.x + xv.y*xv.y + xv.z*xv.z + xv.w*xv.w;
#pragma unroll
    for (int m = 32; m > 0; m >>= 1) s += __shfl_xor(s, m, 64);
    __shared__ float ps[4];
    if ((t & 63) == 0) ps[t >> 6] = s;
    __syncthreads();
    s = ps[0] + ps[1] + ps[2] + ps[3];
    float r = rsqrtf(s * (1.f / (float)D_) + 1e-6f);
    float4 wv = ((const float4*)w)[t];
    bf16* orow = o + (long)row * D_ + t * 4;
    orow[0] = __float2bfloat16(xv.x * r * wv.x);
    orow[1] = __float2bfloat16(xv.y * r * wv.y);
    orow[2] = __float2bfloat16(xv.z * r * wv.z);
    orow[3] = __float2bfloat16(xv.w * r * wv.w);
}

// fused softplus/ld + per-chunk inclusive cumsum
__global__ __launch_bounds__(256) void k_cum(const float* __restrict__ dtr,
                                             const float* __restrict__ dt_bias,
                                             const float* __restrict__ A_log,
                                             float* __restrict__ cum_g,
                                             float* __restrict__ cumlast)
{
    int bid = blockIdx.x;           // b*256 + c*16 + h
    int h = bid & 15, c = (bid >> 4) & 15, b = bid >> 8;
    long rowbase = (long)b * L_ + c * CS_;
    int tid = threadIdx.x;
    __shared__ float cum_s[256];
    float d = dtr[(rowbase + tid) * H_ + h] + dt_bias[h];
    float sp = (d > 20.f) ? d : log1pf(__expf(d));
    cum_s[tid] = -__expf(A_log[h]) * sp;
    __syncthreads();
    for (int off = 1; off < 256; off <<= 1) {
        float add = (tid >= off) ? cum_s[tid - off] : 0.f;
        __syncthreads();
        cum_s[tid] += add;
        __syncthreads();
    }
    cum_g[(rowbase + tid) * H_ + h] = cum_s[tid];
    if (tid == 255) cumlast[bid] = cum_s[255];
}

// fused causal-conv + silu + transpose: val_b [b*L][2048] -> vT [b*2048+d][L]
__global__ void k_vtc(const bf16* __restrict__ val_b, const float* __restrict__ cw,
                      const float* __restrict__ cb, bf16* __restrict__ vT)
{
    __shared__ bf16 tile[35][33];
    int b = blockIdx.z;
    int r0 = blockIdx.x * 32, c0 = blockIdx.y * 32;
    int tid = threadIdx.x;
    for (int idx = tid; idx < 35 * 32; idx += 256) {
        int row = idx >> 5, ch = idx & 31;
        int gl = r0 - 3 + row;
        bf16 v = __float2bfloat16(0.f);
        if (gl >= 0 && gl < L_) v = val_b[((long)b * L_ + gl) * 2048 + c0 + ch];
        tile[row][ch] = v;
    }
    __syncthreads();
    int tx = tid & 31, ty = tid >> 5;
    int l = r0 + tx;
    for (int i = 0; i < 32; i += 8) {
        int ch = c0 + ty + i;
        float4 cwv = ((const float4*)cw)[ch];
        float acc = cb[ch]
                  + cwv.x * __bfloat162float(tile[tx][ty + i])
                  + cwv.y * __bfloat162float(tile[tx + 1][ty + i])
                  + cwv.z * __bfloat162float(tile[tx + 2][ty + i])
                  + cwv.w * __bfloat162float(tile[tx + 3][ty + i]);
        float s = acc / (1.f + __expf(-acc));
        vT[((long)b * 2048 + ch) * L_ + l] = __float2bfloat16(s);
    }
}

// bc_b B-part [b*L][4096 cols 0..2047] -> BT [b*2048 + col][L]
__global__ void k_bt(const bf16* __restrict__ bc, bf16* __restrict__ BT)
{
    __shared__ bf16 tile[32][33];
    int b = blockIdx.z;
    int r0 = blockIdx.x * 32, c0 = blockIdx.y * 32;
    int tx = threadIdx.x & 31, ty = threadIdx.x >> 5;
    for (int i = 0; i < 32; i += 8)
        tile[ty + i][tx] = bc[((long)b * L_ + r0 + ty + i) * 4096 + c0 + tx];
    __syncthreads();
    int l = r0 + tx;
    for (int i = 0; i < 32; i += 8) {
        int col = c0 + ty + i;
        BT[((long)b * 2048 + col) * L_ + l] = tile[tx][ty + i];
    }
}

// U[c][b][h][d][n] = sum_t (v[t,d]*w_t) B[t,n] — MFMA; v scaled in-register; bf16 out
__global__ __launch_bounds__(256, 2) void k_ssd_u2(
    const bf16* __restrict__ vT, const bf16* __restrict__ BT,
    const float* __restrict__ cum_g, const float* __restrict__ cumlast,
    bf16* __restrict__ U)
{
    int bid = blockIdx.x;
    int h = bid & 15, c = (bid >> 4) & 15, b = bid >> 8;
    long rowbase = (long)b * L_ + c * CS_;
    int tid = threadIdx.x;
    __shared__ float w_s[256];
    w_s[tid] = __expf(cumlast[bid] - cum_g[(rowbase + tid) * H_ + h]);
    __syncthreads();
    int lane = tid & 63, wave = tid >> 6;
    int r16 = lane & 15, q8 = (lane >> 4) * 8, rq = (lane >> 4) * 4;
    int d0 = (wave >> 1) * 64, n0 = (wave & 1) * 64;
    const bf16* vb = vT + ((long)b * 2048 + h * 128) * L_ + c * 256;
    const bf16* bb = BT + ((long)b * 2048 + h * 128) * L_ + c * 256;
    floatx4 zero4 = {0.f, 0.f, 0.f, 0.f};
    floatx4 acc[4][4];
#pragma unroll
    for (int i = 0; i < 4; i++)
#pragma unroll
        for (int j = 0; j < 4; j++) acc[i][j] = zero4;
#pragma unroll 2
    for (int ks = 0; ks < 8; ks++) {
        float wv[8];
#pragma unroll
        for (int j = 0; j < 8; j++) wv[j] = w_s[ks * 32 + q8 + j];
        short8 af[4], bq[4];
#pragma unroll
        for (int i = 0; i < 4; i++) {
            short8 raw = *(const short8*)(vb + (long)(d0 + i * 16 + r16) * L_ + ks * 32 + q8);
#pragma unroll
            for (int j = 0; j < 8; j++) {
                float f = bf2f(raw[j]) * wv[j];
                raw[j] = (short)(__float_as_uint(f) >> 16);
            }
            af[i] = raw;
        }
#pragma unroll
        for (int j = 0; j < 4; j++)
            bq[j] = *(const short8*)(bb + (long)(n0 + j * 16 + r16) * L_ + ks * 32 + q8);
#pragma unroll
        for (int i = 0; i < 4; i++)
#pragma unroll
            for (int j = 0; j < 4; j++)
                acc[i][j] = __builtin_amdgcn_mfma_f32_16x16x32_bf16(af[i], bq[j], acc[i][j], 0, 0, 0);
    }
    bf16* up = U + (((long)c * B_ + b) * H_ + h) * 16384;
#pragma unroll
    for (int i = 0; i < 4; i++)
#pragma unroll
        for (int j = 0; j < 4; j++)
#pragma unroll
            for (int r = 0; r < 4; r++)
                up[(d0 + i * 16 + rq + r) * 128 + (n0 + j * 16 + r16)] = __float2bfloat16(acc[i][j][r]);
}

// h recurrence -> bf16 states entering each chunk (vectorized x8)
__global__ void k_ssd2(const bf16* __restrict__ U, const float* __restrict__ cumlast,
                       bf16* __restrict__ hst)
{
    const long tot = (long)B_ * H_ * HD_ * N_;
    long idx = ((long)blockIdx.x * 256 + threadIdx.x) * 8;
    if (idx >= tot) return;
    int bh = (int)(idx >> 14);
    int b = bh >> 4, h = bh & 15;
    float hv[8];
#pragma unroll
    for (int j = 0; j < 8; j++) hv[j] = 0.f;
    for (int c = 0; c < NC_; c++) {
        float ef = __expf(cumlast[b * 256 + c * 16 + h]);
        short8 u = *(const short8*)(U + c * tot + idx);
        short8 o;
#pragma unroll
        for (int j = 0; j < 8; j++) {
            o[j] = f2bf(hv[j]);
            hv[j] = ef * hv[j] + bf2f(u[j]);
        }
        *(short8*)(hst + c * tot + idx) = o;
    }
}

// Fused intra+inter SSD output, flash-style MFMA. Writes gated bf16 yg.
__global__ __launch_bounds__(256, 2) void k_ssd_y(
    const bf16* __restrict__ bc_b, const bf16* __restrict__ vT,
    const bf16* __restrict__ hst, const float* __restrict__ cum_g,
    const float* __restrict__ Dskip, const bf16* __restrict__ gate_b,
    bf16* __restrict__ yg)
{
    int bid = blockIdx.x;
    int h = bid & 15, c = (bid >> 4) & 15, b = bid >> 8;
    long rowbase = (long)b * L_ + c * CS_;
    int tid = threadIdx.x, lane = tid & 63, wave = tid >> 6;
    int r16 = lane & 15, q8 = (lane >> 4) * 8, rq = (lane >> 4) * 4;
    int wt = (wave >> 1) * 32, wmS = (wave & 1) * 32, wd = (wave & 1) * 64;

    __shared__ float cum_s[256];
    __shared__ __align__(16) bf16 Ss[64][72];

    cum_s[tid] = cum_g[(rowbase + tid) * H_ + h];
    __syncthreads();

    const bf16* Cb  = bc_b + rowbase * 4096 + 2048 + h * 128;
    const bf16* Bb  = bc_b + rowbase * 4096 + h * 128;
    const bf16* vTb = vT + ((long)b * 2048 + h * 128) * L_ + c * 256;
    const bf16* hp  = hst + (((long)c * B_ + b) * H_ + h) * 16384;

    floatx4 zero4 = {0.f, 0.f, 0.f, 0.f};

    for (int tt = 0; tt < 4; tt++) {
        int tbase = tt * 64;
        short8 caf[2][4];
#pragma unroll
        for (int i = 0; i < 2; i++)
#pragma unroll
            for (int ks = 0; ks < 4; ks++)
                caf[i][ks] = *(const short8*)(Cb + (long)(tbase + wt + i * 16 + r16) * 4096 + ks * 32 + q8);

        floatx4 yacc[2][4];
#pragma unroll
        for (int i = 0; i < 2; i++)
#pragma unroll
            for (int j = 0; j < 4; j++) yacc[i][j] = zero4;
#pragma unroll
        for (int ks = 0; ks < 4; ks++)
#pragma unroll
            for (int j = 0; j < 4; j++) {
                short8 hq = *(const short8*)(hp + (long)(wd + j * 16 + r16) * 128 + ks * 32 + q8);
#pragma unroll
                for (int i = 0; i < 2; i++)
                    yacc[i][j] = __builtin_amdgcn_mfma_f32_16x16x32_bf16(caf[i][ks], hq, yacc[i][j], 0, 0, 0);
            }
        float texp[2][4];
#pragma unroll
        for (int i = 0; i < 2; i++)
#pragma unroll
            for (int r = 0; r < 4; r++)
                texp[i][r] = __expf(cum_s[tbase + wt + i * 16 + rq + r]);
#pragma unroll
        for (int i = 0; i < 2; i++)
#pragma unroll
            for (int j = 0; j < 4; j++)
#pragma unroll
                for (int r = 0; r < 4; r++) yacc[i][j][r] *= texp[i][r];

        for (int mt = 0; mt <= tt; mt++) {
            int mbase = mt * 64;
            floatx4 sacc[2][2];
#pragma unroll
            for (int i = 0; i < 2; i++)
#pragma unroll
                for (int j = 0; j < 2; j++) sacc[i][j] = zero4;
#pragma unroll
            for (int ks = 0; ks < 4; ks++) {
                short8 bq[2];
#pragma unroll
                for (int j = 0; j < 2; j++)
                    bq[j] = *(const short8*)(Bb + (long)(mbase + wmS + j * 16 + r16) * 4096 + ks * 32 + q8);
#pragma unroll
                for (int i = 0; i < 2; i++)
#pragma unroll
                    for (int j = 0; j < 2; j++)
                        sacc[i][j] = __builtin_amdgcn_mfma_f32_16x16x32_bf16(caf[i][ks], bq[j], sacc[i][j], 0, 0, 0);
            }
            __syncthreads();
#pragma unroll
            for (int i = 0; i < 2; i++)
#pragma unroll
                for (int r = 0; r < 4; r++) {
                    int trow = wt + i * 16 + rq + r;
                    float ct = cum_s[tbase + trow];
#pragma unroll
                    for (int j = 0; j < 2; j++) {
                        int mcol = mbase + wmS + j * 16 + r16;
                        float val = (mcol <= tbase + trow) ? sacc[i][j][r] * __expf(ct - cum_s[mcol]) : 0.f;
                        Ss[trow][wmS + j * 16 + r16] = __float2bfloat16(val);
                    }
                }
            __syncthreads();
#pragma unroll
            for (int ks = 0; ks < 2; ks++) {
                short8 saf[2];
#pragma unroll
                for (int i = 0; i < 2; i++)
                    saf[i] = *(const short8*)&Ss[wt + i * 16 + r16][ks * 32 + q8];
#pragma unroll
                for (int j = 0; j < 4; j++) {
                    short8 vq = *(const short8*)(vTb + (long)(wd + j * 16 + r16) * L_ + mbase + ks * 32 + q8);
#pragma unroll
                    for (int i = 0; i < 2; i++)
                        yacc[i][j] = __builtin_amdgcn_mfma_f32_16x16x32_bf16(saf[i], vq, yacc[i][j], 0, 0, 0);
                }
            }
        }
#pragma unroll
        for (int i = 0; i < 2; i++)
#pragma unroll
            for (int r = 0; r < 4; r++) {
                int t = tbase + wt + i * 16 + rq + r;
                long grow = (rowbase + t) * 2048 + h * 128;
#pragma unroll
                for (int j = 0; j < 4; j++) {
                    int d = wd + j * 16 + r16;
                    float vv = __bfloat162float(vTb[(long)d * L_ + t]);
                    float y = yacc[i][j][r] + Dskip[h * 128 + d] * vv;
                    float g = __bfloat162float(gate_b[grow + d]);
                    float sg = g / (1.f + __expf(-g));
                    yg[grow + d] = __float2bfloat16(y * sg);
                }
            }
    }
}

// merged transposes: vTm[d][l] = vbuf[l][d];  wkgT[d][l] = gw[l%256]*out[l-1][d]
__global__ void k_trans2(const bf16* __restrict__ vbuf, const bf16* __restrict__ outg,
                         const float* __restrict__ scr,
                         bf16* __restrict__ vTm, bf16* __restrict__ wkgT)
{
    __shared__ bf16 tv[32][33];
    __shared__ bf16 tw[32][33];
    int b = blockIdx.z;
    const bf16* srcv = vbuf + (long)b * L_ * D_;
    const bf16* srco = outg + (long)b * L_ * D_;
    int r0 = blockIdx.x * 32, c0 = blockIdx.y * 32;
    int tx = threadIdx.x & 31, ty = threadIdx.x >> 5;
    for (int i = 0; i < 32; i += 8) {
        int rr = r0 + ty + i;
        tv[ty + i][tx] = srcv[(long)rr * D_ + c0 + tx];
        float g = scr[272 + (rr & 255)];
        float w = (rr == 0) ? 0.f : __bfloat162float(srco[(long)(rr - 1) * D_ + c0 + tx]) * g;
        tw[ty + i][tx] = __float2bfloat16(w);
    }
    __syncthreads();
    bf16* dv = vTm + (long)b * D_ * L_;
    bf16* dw = wkgT + (long)b * D_ * L_;
    for (int i = 0; i < 32; i += 8) {
        long o = (long)(c0 + ty + i) * L_ + r0 + tx;
        dv[o] = tv[tx][ty + i];
        dw[o] = tw[tx][ty + i];
    }
}

// W recurrence, in place, vectorized x8
__global__ void k_m2(bf16* __restrict__ UwW, const float* __restrict__ scr)
{
    const long tot = (long)B_ * D_ * D_;
    long idx = ((long)blockIdx.x * 256 + threadIdx.x) * 8;
    if (idx >= tot) return;
    float gMC = scr[2];
    float w[8];
#pragma unroll
    for (int j = 0; j < 8; j++) w[j] = 0.f;
    for (int c = 0; c < NC_; c++) {
        short8 u = *(const short8*)(UwW + c * tot + idx);
        short8 o;
#pragma unroll
        for (int j = 0; j < 8; j++) {
            o[j] = f2bf(w[j]);
            w[j] = gMC * w[j] + bf2f(u[j]);
        }
        *(short8*)(UwW + c * tot + idx) = o;
    }
}

// ---------------------------------------------------------------------------
// Host side
// ---------------------------------------------------------------------------
static inline int cdiv_i(long a, long b) { return (int)((a + b - 1) / b); }

static void run_gemm(hipStream_t st, int epi, const bf16* A, const bf16* Bt,
                     float* C, bf16* CB, bf16* CB2, bf16* CB3,
                     const float* add0, const float* add1, const bf16* add0b,
                     const float* scr, int M, int N, int K,
                     long lda, long ldb, long ldc, int nbatch, int zinner,
                     long a_zo, long a_zi, long b_zo, long b_zi, long c_zo, long c_zi,
                     int tri = 0)
{
    GemmP p;
    p.A = A; p.Bt = Bt; p.C = C; p.CB = CB; p.CB2 = CB2; p.CB3 = CB3;
    p.add0 = add0; p.add1 = add1; p.add0b = add0b; p.scr = scr;
    p.lda = lda; p.ldb = ldb; p.ldc = ldc;
    p.M = M; p.N = N; p.K = K; p.zinner = zinner; p.tri = tri;
    p.a_zo = a_zo; p.a_zi = a_zi; p.b_zo = b_zo; p.b_zi = b_zi; p.c_zo = c_zo; p.c_zi = c_zi;
    dim3 g(cdiv_i(N, 128), cdiv_i(M, 128), nbatch);
    dim3 b(256);
    switch (epi) {
        case 0: gemm_bt<0><<<g, b, 0, st>>>(p); break;
        case 2: gemm_bt<2><<<g, b, 0, st>>>(p); break;
        case 3: gemm_bt<3><<<g, b, 0, st>>>(p); break;
        case 4: gemm_bt<4><<<g, b, 0, st>>>(p); break;
        case 6: gemm_bt<6><<<g, b, 0, st>>>(p); break;
        case 7: gemm_bt<7><<<g, b, 0, st>>>(p); break;
        case 8: gemm_bt<8><<<g, b, 0, st>>>(p); break;
    }
}

extern "C" void kernel_launch(void* const* d_in, const int* in_sizes, int n_in,
                              void* d_out, int out_size, void* d_ws, size_t ws_size,
                              hipStream_t stream)
{
    const float* x       = (const float*)d_in[0];
    const float* norm_w  = (const float*)d_in[1];
    const float* w_in    = (const float*)d_in[2];
    const float* conv_w  = (const float*)d_in[3];
    const float* conv_b  = (const float*)d_in[4];
    const float* A_log   = (const float*)d_in[5];
    const float* dt_bias = (const float*)d_in[6];
    const float* D_skip  = (const float*)d_in[7];
    const float* w_out   = (const float*)d_in[8];
    const float* w_write = (const float*)d_in[9];
    const float* w_read  = (const float*)d_in[10];
    const float* decay   = (const float*)d_in[11];
    float* outp = (float*)d_out;

    // ---- workspace layout (lifetime overlays) ----
    const size_t SZ_SCR  = 4096;
    const size_t SZ_DT   = (size_t)B_ * L_ * H_ * 4;
    const size_t SZ_CUML = 2048;
    const size_t SZ_WOUT = (size_t)D_ * DI_ * 2;
    const size_t SZ_WSML = (size_t)D_ * D_ * 2;
    const size_t SZ_R1   = (size_t)B_ * L_ * 2048 * 2;
    const size_t SZ_R2   = SZ_R1;
    const size_t SZ_R3   = (size_t)B_ * L_ * 4096 * 2;
    const size_t SZ_R4   = (size_t)B_ * L_ * D_ * 2 + (size_t)PROJ_ * D_ * 2;
    const size_t SZ_R5   = (size_t)B_ * L_ * 2048 * 4;

    size_t o = 0;
    auto take = [&](size_t sz) { size_t r = o; o += (sz + 255) & ~(size_t)255; return r; };
    const size_t O_SCR = take(SZ_SCR);
    const size_t O_DT  = take(SZ_DT);
    const size_t O_LD  = take(SZ_DT);
    const size_t O_CUM = take(SZ_DT);
    const size_t O_CL  = take(SZ_CUML);
    const size_t O_WO  = take(SZ_WOUT);
    const size_t O_WW  = take(SZ_WSML);
    const size_t O_WR  = take(SZ_WSML);
    const size_t O_R1  = take(SZ_R1);
    const size_t O_R2  = take(SZ_R2);
    const size_t O_R3  = take(SZ_R3);
    const size_t O_R4  = take(SZ_R4);
    const size_t O_R5  = take(SZ_R5);
    const size_t NEED = o;
    if (ws_size < NEED) return;
    (void)O_LD;

    char* ws = (char*)d_ws;
    float* scr     = (float*)(ws + O_SCR);
    float* dt_raw  = (float*)(ws + O_DT);
    float* cum_g   = (float*)(ws + O_CUM);
    float* cumlast = (float*)(ws + O_CL);
    bf16*  w_out_b   = (bf16*)(ws + O_WO);
    bf16*  w_write_b = (bf16*)(ws + O_WW);
    bf16*  w_read_b  = (bf16*)(ws + O_WR);

    bf16*  val_b   = (bf16*)(ws + O_R1);
    bf16*  yg_b    = (bf16*)(ws + O_R1);
    bf16*  hst_b   = (bf16*)(ws + O_R1 + (size_t)B_ * L_ * D_ * 2);
    bf16*  Sm_b    = (bf16*)(ws + O_R1);
    bf16*  intra_b = (bf16*)(ws + O_R1 + (size_t)NC_ * B_ * MC_ * MC_ * 2);
    bf16*  gate_b  = (bf16*)(ws + O_R2);
    bf16*  out_b   = (bf16*)(ws + O_R2);
    bf16*  wk_b    = (bf16*)(ws + O_R2 + (size_t)B_ * L_ * D_ * 2);
    bf16*  reads_b = wk_b;
    bf16*  bc_b    = (bf16*)(ws + O_R3);
    bf16*  UwW     = (bf16*)(ws + O_R3);
    bf16*  xn_b    = (bf16*)(ws + O_R4);
    bf16*  w_in_b  = (bf16*)(ws + O_R4 + (size_t)B_ * L_ * D_ * 2);
    bf16*  U_ssd   = (bf16*)(ws + O_R4);
    bf16*  vT_g    = (bf16*)(ws + O_R5);
    bf16*  BT_g    = (bf16*)(ws + O_R5 + (size_t)B_ * L_ * 2048 * 2);
    bf16*  vbuf_b  = (bf16*)(ws + O_R5);
    bf16*  vTm     = (bf16*)(ws + O_R5 + (size_t)B_ * L_ * D_ * 4);
    bf16*  wkgT    = (bf16*)(ws + O_R5 + (size_t)B_ * L_ * D_ * 4 + (size_t)B_ * L_ * D_ * 2);

    k_gamma<<<1, 256, 0, stream>>>(decay, scr);
    {
        long n0 = (long)PROJ_ * D_ / 4, n1 = (long)D_ * DI_ / 4;
        long n2 = (long)D_ * D_ / 4,   n3 = n2;
        k_f2ball<<<cdiv_i(n0 + n1 + n2 + n3, 256), 256, 0, stream>>>(
            w_in, w_in_b, n0, w_out, w_out_b, n1, w_write, w_write_b, n2, w_read, w_read_b, n3);
    }
    k_rmsnorm<<<B_ * L_, 256, 0, stream>>>(x, norm_w, xn_b);
    // proj
    run_gemm(stream, 2, xn_b, w_in_b, dt_raw, val_b, gate_b, bc_b, nullptr, nullptr, nullptr, nullptr,
             B_ * L_, PROJ_, D_, D_, D_, 0, 1, 1, 0, 0, 0, 0, 0, 0);
    k_cum<<<B_ * NC_ * H_, 256, 0, stream>>>(dt_raw, dt_bias, A_log, cum_g, cumlast);
    // fused conv+silu+transpose, B transpose
    k_vtc<<<dim3(L_ / 32, DI_ / 32, B_), 256, 0, stream>>>(val_b, conv_w, conv_b, vT_g);
    k_bt<<<dim3(L_ / 32, DI_ / 32, B_), 256, 0, stream>>>(bc_b, BT_g);
    // SSD
    k_ssd_u2<<<B_ * NC_ * H_, 256, 0, stream>>>(vT_g, BT_g, cum_g, cumlast, U_ssd);
    k_ssd2<<<cdiv_i((long)B_ * H_ * HD_ * N_ / 8, 256), 256, 0, stream>>>(U_ssd, cumlast, hst_b);
    k_ssd_y<<<B_ * NC_ * H_, 256, 0, stream>>>(bc_b, vT_g, hst_b, cum_g, D_skip, gate_b, yg_b);
    // out projection (bf16 + fused shift into wk)
    run_gemm(stream, 8, yg_b, w_out_b, nullptr, out_b, wk_b, nullptr, nullptr, nullptr, nullptr, nullptr,
             B_ * L_, D_, DI_, DI_, DI_, D_, 1, 1, 0, 0, 0, 0, 0, 0);
    // memory scan
    run_gemm(stream, 6, out_b, w_write_b, nullptr, vbuf_b, nullptr, nullptr, nullptr, nullptr, nullptr, nullptr,
             B_ * L_, D_, D_, D_, D_, D_, 1, 1, 0, 0, 0, 0, 0, 0);
    k_trans2<<<dim3(L_ / 32, D_ / 32, B_), 256, 0, stream>>>(vbuf_b, out_b, scr, vTm, wkgT);
    run_gemm(stream, 6, vTm, wkgT, nullptr, UwW, nullptr, nullptr, nullptr, nullptr, nullptr, nullptr,
             D_, D_, MC_, L_, L_, D_, B_ * NC_, NC_,
             (long)D_ * L_, MC_, (long)D_ * L_, MC_, (long)D_ * D_, (long)B_ * D_ * D_);
    k_m2<<<cdiv_i((long)B_ * D_ * D_ / 8, 256), 256, 0, stream>>>(UwW, scr);
    run_gemm(stream, 3, out_b, wk_b, nullptr, Sm_b, nullptr, nullptr, nullptr, nullptr, nullptr, scr,
             MC_, MC_, D_, D_, D_, MC_, B_ * NC_, NC_,
             (long)L_ * D_, (long)MC_ * D_, (long)L_ * D_, (long)MC_ * D_,
             (long)MC_ * MC_, (long)B_ * MC_ * MC_, 1);
    run_gemm(stream, 6, Sm_b, vTm, nullptr, intra_b, nullptr, nullptr, nullptr, nullptr, nullptr, nullptr,
             MC_, D_, MC_, MC_, L_, D_, B_ * NC_, NC_,
             (long)MC_ * MC_, (long)B_ * MC_ * MC_, (long)D_ * L_, MC_,
             (long)L_ * D_, (long)MC_ * D_, 2);
    run_gemm(stream, 4, out_b, UwW, nullptr, reads_b, nullptr, nullptr, nullptr, nullptr, intra_b, scr,
             MC_, D_, D_, D_, D_, D_, B_ * NC_, NC_,
             (long)L_ * D_, (long)MC_ * D_, (long)D_ * D_, (long)B_ * D_ * D_,
             (long)L_ * D_, (long)MC_ * D_);
    // final: d_out = x + out + 0.5 * reads @ w_read^T
    run_gemm(stream, 7, reads_b, w_read_b, outp, nullptr, nullptr, nullptr, x, nullptr, out_b, nullptr,
             B_ * L_, D_, D_, D_, D_, D_, 1, 1, 0, 0, 0, 0, 0, 0);
}

// Round 9
// 737.163 us; speedup vs baseline: 1.0259x; 1.0259x over previous
//
#include <hip/hip_runtime.h>
#include <hip/hip_bf16.h>

typedef __hip_bfloat16 bf16;
typedef __attribute__((ext_vector_type(8))) short short8;
typedef __attribute__((ext_vector_type(4))) float floatx4;
typedef __attribute__((ext_vector_type(16))) float floatx16;

#define B_ 2
#define L_ 4096
#define D_ 1024
#define DI_ 2048
#define H_ 16
#define HD_ 128
#define N_ 128
#define CS_ 256
#define MC_ 256
#define NC_ 16
#define PROJ_ 8208

__device__ __forceinline__ float bf2f(short s) {
    return __uint_as_float(((unsigned)(unsigned short)s) << 16);
}
__device__ __forceinline__ short f2bf(float f) {
    __hip_bfloat16 h = __float2bfloat16(f);
    return *(short*)&h;
}

__device__ __forceinline__ void gl_lds16(const void* g, void* s) {
    __builtin_amdgcn_global_load_lds(
        (const __attribute__((address_space(1))) void*)g,
        (__attribute__((address_space(3))) void*)s, 16, 0, 0);
}

// ---------------------------------------------------------------------------
// Generic bf16 MFMA GEMM: C[M,N] = A[M,K] @ Bt[N,K]^T  (both row-major, K contig)
// 128x128 tile, 4 waves, 32x32x16 MFMA, global_load_lds(16B) staging,
// XCD-aware supertile remap, XOR LDS bank swizzle.
// tri: 0=none, 1=output causal-masked (Sm), 2=A block-lower-tri (intra).
// EPI 2: proj — val tiles bounce-transposed to CB(valT), gate->CB2, BC->CB3
//        (B tiles also bounce to CB4=BT), dt head -> C (fp32).
// EPI 9: transposed-only output via LDS bounce to CB (vTm).
// ---------------------------------------------------------------------------
struct GemmP {
    const bf16* A; const bf16* Bt;
    float* C; bf16* CB; bf16* CB2; bf16* CB3; bf16* CB4;
    const float* add0; const float* add1; const bf16* add0b; const float* scr;
    long lda, ldb, ldc;
    int M, N, K, zinner, tri;
    long a_zo, a_zi, b_zo, b_zi, c_zo, c_zi;
};

template<int EPI>
__global__ __launch_bounds__(256, 2) void gemm_bt(GemmP p)
{
    // ---- XCD-aware tile remap (exact bijection grid -> tiles) ----
    int NT = gridDim.x, MT = gridDim.y;
    long T = (long)NT * MT * gridDim.z;
    long flat = ((long)blockIdx.z * MT + blockIdx.y) * NT + blockIdx.x;
    int xcd = (int)(flat & 7);
    long q = flat >> 3;
    long Tq = T >> 3; int Tr = (int)(T & 7);
    long tile = (long)xcd * Tq + (long)(xcd < Tr ? xcd : Tr) + q;
    long per_z = (long)NT * MT;
    int z = (int)(tile / per_z);
    int t2 = (int)(tile - (long)z * per_z);
    int FG = NT >> 3;
    int g, width, within;
    if (t2 < FG * MT * 8) { g = t2 / (MT * 8); width = 8; within = t2 - g * MT * 8; }
    else                  { g = FG; width = NT - FG * 8; within = t2 - FG * MT * 8; }
    int m_outer = within / (8 * width);
    int hb = MT - m_outer * 8; if (hb > 8) hb = 8;
    int inner = within - m_outer * 8 * width;
    int n_in = inner / hb, m_in = inner - n_in * hb;
    int m0 = (m_outer * 8 + m_in) * 128;
    int n0 = (g * 8 + n_in) * 128;

    int zo = z / p.zinner, zi = z % p.zinner;
    const bf16* A  = p.A  + (long)zo * p.a_zo + (long)zi * p.a_zi;
    const bf16* Bt = p.Bt + (long)zo * p.b_zo + (long)zi * p.b_zi;
    long coff = (long)zo * p.c_zo + (long)zi * p.c_zi;

    int tid = threadIdx.x;
    int lane = tid & 63, wave = tid >> 6;
    int wm = (wave >> 1) * 64, wn = (wave & 1) * 64;
    int ln31 = lane & 31, hi = lane >> 5;

    __shared__ __align__(16) bf16 Sh[2 * 128 * 64];   // staging / epilogue bounce
    bf16* As = Sh;
    bf16* Bs = Sh + 128 * 64;

    // fully-masked Sm tile: write zeros, skip compute
    if (p.tri == 1 && n0 >= m0 + 128) {
        if (EPI == 3) {
#pragma unroll
            for (int i = 0; i < 2; i++)
#pragma unroll
                for (int j = 0; j < 2; j++)
#pragma unroll
                    for (int r = 0; r < 16; r++) {
                        int gm = m0 + wm + i * 32 + (r & 3) + 8 * (r >> 2) + 4 * hi;
                        int gn = n0 + wn + j * 32 + ln31;
                        if (gm < p.M && gn < p.N)
                            p.CB[coff + (long)gm * p.ldc + gn] = __float2bfloat16(0.f);
                    }
        }
        return;
    }
    int Keff = (p.tri == 2) ? (m0 + 128 < p.K ? m0 + 128 : p.K) : p.K;

    floatx16 acc[2][2];
#pragma unroll
    for (int i = 0; i < 2; i++)
#pragma unroll
        for (int j = 0; j < 2; j++)
#pragma unroll
            for (int r = 0; r < 16; r++) acc[i][j][r] = 0.f;

    int lrow = lane >> 3;
    int lc = ((lane & 7) ^ lrow) * 8;     // XOR-swizzled column (write side)
    int wrow = wave * 32;
    int rx = lane & 7;                    // read-side xor key

    for (int k0 = 0; k0 < Keff; k0 += 64) {
#pragma unroll
        for (int t = 0; t < 4; t++) {
            int row = wrow + t * 8 + lrow;
            gl_lds16(A + (long)(m0 + row) * p.lda + k0 + lc, &As[(wrow + t * 8) * 64]);
            int bn = n0 + row; if (bn > p.N - 1) bn = p.N - 1;
            gl_lds16(Bt + (long)bn * p.ldb + k0 + lc, &Bs[(wrow + t * 8) * 64]);
        }
        __syncthreads();
#pragma unroll
        for (int ks = 0; ks < 64; ks += 16) {
            int lb = (ks >> 3) + hi;
            int po = ((lb ^ rx) << 3);
            short8 af[2], bq[2];
#pragma unroll
            for (int i = 0; i < 2; i++)
                af[i] = *(const short8*)&As[(wm + i * 32 + ln31) * 64 + po];
#pragma unroll
            for (int j = 0; j < 2; j++)
                bq[j] = *(const short8*)&Bs[(wn + j * 32 + ln31) * 64 + po];
#pragma unroll
            for (int i = 0; i < 2; i++)
#pragma unroll
                for (int j = 0; j < 2; j++)
                    acc[i][j] = __builtin_amdgcn_mfma_f32_32x32x16_bf16(af[i], bq[j], acc[i][j], 0, 0, 0);
        }
        __syncthreads();
    }

    if (EPI != 9) {
#pragma unroll
        for (int i = 0; i < 2; i++) {
#pragma unroll
            for (int j = 0; j < 2; j++) {
#pragma unroll
                for (int r = 0; r < 16; r++) {
                    int gm = m0 + wm + i * 32 + (r & 3) + 8 * (r >> 2) + 4 * hi;
                    int gn = n0 + wn + j * 32 + ln31;
                    if (gm >= p.M || gn >= p.N) continue;
                    float a = acc[i][j][r];
                    if (EPI == 0) {
                        p.C[coff + (long)gm * p.ldc + gn] = a;
                    } else if (EPI == 2) {            // proj split (val handled by bounce)
                        if (gn >= 8192)     p.C  [(long)gm * 16   + (gn - 8192)] = a;
                        else if (gn >= 4096) p.CB3[(long)gm * 4096 + (gn - 4096)] = __float2bfloat16(a);
                        else if (gn >= 2048) p.CB2[(long)gm * 2048 + (gn - 2048)] = __float2bfloat16(a);
                    } else if (EPI == 3) {            // Mmem causal decay mask -> bf16
                        float lg = p.scr[1];
                        float v = (gm > gn) ? a * __expf((float)(gm - 1 - gn) * lg) : 0.f;
                        p.CB[coff + (long)gm * p.ldc + gn] = __float2bfloat16(v);
                    } else if (EPI == 4) {            // inter: acc*gp[m] + intra(bf16) -> bf16
                        long ix = coff + (long)gm * p.ldc + gn;
                        float t = a * p.scr[16 + gm] + __bfloat162float(p.add0b[ix]);
                        p.CB[ix] = __float2bfloat16(t);
                    } else if (EPI == 6) {            // bf16 only
                        p.CB[coff + (long)gm * p.ldc + gn] = __float2bfloat16(a);
                    } else if (EPI == 7) {            // final: x(f32) + out(bf16) + 0.5*acc
                        long ix = (long)gm * p.ldc + gn;
                        p.C[ix] = p.add0[ix] + __bfloat162float(p.add0b[ix]) + 0.5f * a;
                    } else if (EPI == 8) {            // out_b + fused shift into wk
                        long ix = (long)gm * p.ldc + gn;
                        bf16 v = __float2bfloat16(a);
                        p.CB[ix] = v;
                        int l = gm & (L_ - 1);
                        if (l != L_ - 1) p.CB2[ix + p.ldc] = v;
                        if (l == 0) p.CB2[ix] = __float2bfloat16(0.f);
                    }
                }
            }
        }
    }

    // ---- transposed-output bounce (EPI2 val/B tiles; EPI9 all tiles) ----
    if (EPI == 2 || EPI == 9) {
        bool doT = (EPI == 9) || (n0 < 2048) || (n0 >= 4096 && n0 < 6144);
        if (doT) {
#pragma unroll
            for (int i = 0; i < 2; i++)
#pragma unroll
                for (int j = 0; j < 2; j++)
#pragma unroll
                    for (int r = 0; r < 16; r++) {
                        int lr = wm + i * 32 + (r & 3) + 8 * (r >> 2) + 4 * hi;
                        int lcn = wn + j * 32 + ln31;
                        Sh[lr * 128 + lcn] = __float2bfloat16(acc[i][j][r]);
                    }
            __syncthreads();
            int bloc = m0 >> 12;              // m0 / L_
            int l0 = m0 & (L_ - 1);
            int dl = tid & 127, lh = tid >> 7;
            bf16* dst;
            if (EPI == 9)        dst = p.CB  + ((long)bloc * D_   + n0          + dl) * L_ + l0;
            else if (n0 < 2048)  dst = p.CB  + ((long)bloc * 2048 + n0          + dl) * L_ + l0;
            else                 dst = p.CB4 + ((long)bloc * 2048 + (n0 - 4096) + dl) * L_ + l0;
            const short* shs = (const short*)Sh;
#pragma unroll
            for (int s = 0; s < 8; s++) {
                int ls = lh * 64 + s * 8;
                short8 v;
#pragma unroll
                for (int u = 0; u < 8; u++) v[u] = shs[(ls + u) * 128 + dl];
                *(short8*)(dst + ls) = v;
            }
        }
    }
}

// ---------------------------------------------------------------------------
// Elementwise / helper kernels
// ---------------------------------------------------------------------------
__global__ void k_gamma(const float* decay, float* scr)
{
    int t = threadIdx.x;
    float g = 1.f / (1.f + expf(-decay[0]));
    float lg = logf(g);
    if (t == 0) { scr[0] = g; scr[1] = lg; scr[2] = expf(256.f * lg); }
    scr[16 + t]  = expf(lg * (float)t);          // gp
    scr[272 + t] = expf(lg * (float)(255 - t));  // gw
}

__global__ void k_f2ball(const float* __restrict__ s0, bf16* __restrict__ d0, long n0,
                         const float* __restrict__ s1, bf16* __restrict__ d1, long n1,
                         const float* __restrict__ s2, bf16* __restrict__ d2, long n2,
                         const float* __restrict__ s3, bf16* __restrict__ d3, long n3)
{
    long i = (long)blockIdx.x * 256 + threadIdx.x;
    const float* s; bf16* d; long rel = i;
    if (rel < n0) { s = s0; d = d0; }
    else { rel -= n0;
        if (rel < n1) { s = s1; d = d1; }
        else { rel -= n1;
            if (rel < n2) { s = s2; d = d2; }
            else { rel -= n2; if (rel >= n3) return; s = s3; d = d3; }
        }
    }
    float4 v = ((const float4*)s)[rel];
    bf16* o = d + rel * 4;
    o[0] = __float2bfloat16(v.x); o[1] = __float2bfloat16(v.y);
    o[2] = __float2bfloat16(v.z); o[3] = __float2bfloat16(v.w);
}

__global__ __launch_bounds__(256) void k_rmsnorm(const float* __restrict__ x,
                                                 const float* __restrict__ w,
                                                 bf16* __restrict__ o)
{
    int row = blockIdx.x, t = threadIdx.x;
    float4 xv = ((const float4*)(x + (long)row * D_))[t];
    float s = xv.x*xv.x + xv.y*xv.y + xv.z*xv.z + xv.w*xv.w;
#pragma unroll
    for (int m = 32; m > 0; m >>= 1) s += __shfl_xor(s, m, 64);
    __shared__ float ps[4];
    if ((t & 63) == 0) ps[t >> 6] = s;
    __syncthreads();
    s = ps[0] + ps[1] + ps[2] + ps[3];
    float r = rsqrtf(s * (1.f / (float)D_) + 1e-6f);
    float4 wv = ((const float4*)w)[t];
    bf16* orow = o + (long)row * D_ + t * 4;
    orow[0] = __float2bfloat16(xv.x * r * wv.x);
    orow[1] = __float2bfloat16(xv.y * r * wv.y);
    orow[2] = __float2bfloat16(xv.z * r * wv.z);
    orow[3] = __float2bfloat16(xv.w * r * wv.w);
}

// fused softplus/ld + per-chunk inclusive cumsum
__global__ __launch_bounds__(256) void k_cum(const float* __restrict__ dtr,
                                             const float* __restrict__ dt_bias,
                                             const float* __restrict__ A_log,
                                             float* __restrict__ cum_g,
                                             float* __restrict__ cumlast)
{
    int bid = blockIdx.x;           // b*256 + c*16 + h
    int h = bid & 15, c = (bid >> 4) & 15, b = bid >> 8;
    long rowbase = (long)b * L_ + c * CS_;
    int tid = threadIdx.x;
    __shared__ float cum_s[256];
    float d = dtr[(rowbase + tid) * H_ + h] + dt_bias[h];
    float sp = (d > 20.f) ? d : log1pf(__expf(d));
    cum_s[tid] = -__expf(A_log[h]) * sp;
    __syncthreads();
    for (int off = 1; off < 256; off <<= 1) {
        float add = (tid >= off) ? cum_s[tid - off] : 0.f;
        __syncthreads();
        cum_s[tid] += add;
        __syncthreads();
    }
    cum_g[(rowbase + tid) * H_ + h] = cum_s[tid];
    if (tid == 255) cumlast[bid] = cum_s[255];
}

// conv+silu on transposed val: valT [b*2048+ch][L] -> vT same layout
__global__ void k_vtc2(const bf16* __restrict__ valT, const float* __restrict__ cw,
                       const float* __restrict__ cb, bf16* __restrict__ vT)
{
    int row = blockIdx.y;                 // b*2048 + ch
    int ch = row & 2047;
    long base = (long)row * L_;
    int l0 = blockIdx.x * 2048 + threadIdx.x * 8;
    short8 cur = *(const short8*)(valT + base + l0);
    short8 prev;
#pragma unroll
    for (int u = 0; u < 8; u++) prev[u] = 0;
    if (l0 >= 8) prev = *(const short8*)(valT + base + l0 - 8);
    float4 cwv = ((const float4*)cw)[ch];
    float bias = cb[ch];
    float v[11];
    v[0] = bf2f(prev[5]); v[1] = bf2f(prev[6]); v[2] = bf2f(prev[7]);
#pragma unroll
    for (int u = 0; u < 8; u++) v[3 + u] = bf2f(cur[u]);
    short8 o;
#pragma unroll
    for (int u = 0; u < 8; u++) {
        float a = bias + cwv.x * v[u] + cwv.y * v[u + 1] + cwv.z * v[u + 2] + cwv.w * v[u + 3];
        float s = a / (1.f + __expf(-a));
        o[u] = f2bf(s);
    }
    *(short8*)(vT + base + l0) = o;
}

// U[c][b][h][d][n] = sum_t (v[t,d]*w_t) B[t,n] — MFMA; v scaled in-register; bf16 out
__global__ __launch_bounds__(256, 2) void k_ssd_u2(
    const bf16* __restrict__ vT, const bf16* __restrict__ BT,
    const float* __restrict__ cum_g, const float* __restrict__ cumlast,
    bf16* __restrict__ U)
{
    int bid = blockIdx.x;
    int h = bid & 15, c = (bid >> 4) & 15, b = bid >> 8;
    long rowbase = (long)b * L_ + c * CS_;
    int tid = threadIdx.x;
    __shared__ float w_s[256];
    w_s[tid] = __expf(cumlast[bid] - cum_g[(rowbase + tid) * H_ + h]);
    __syncthreads();
    int lane = tid & 63, wave = tid >> 6;
    int r16 = lane & 15, q8 = (lane >> 4) * 8, rq = (lane >> 4) * 4;
    int d0 = (wave >> 1) * 64, n0 = (wave & 1) * 64;
    const bf16* vb = vT + ((long)b * 2048 + h * 128) * L_ + c * 256;
    const bf16* bb = BT + ((long)b * 2048 + h * 128) * L_ + c * 256;
    floatx4 zero4 = {0.f, 0.f, 0.f, 0.f};
    floatx4 acc[4][4];
#pragma unroll
    for (int i = 0; i < 4; i++)
#pragma unroll
        for (int j = 0; j < 4; j++) acc[i][j] = zero4;
#pragma unroll 2
    for (int ks = 0; ks < 8; ks++) {
        float wv[8];
#pragma unroll
        for (int j = 0; j < 8; j++) wv[j] = w_s[ks * 32 + q8 + j];
        short8 af[4], bq[4];
#pragma unroll
        for (int i = 0; i < 4; i++) {
            short8 raw = *(const short8*)(vb + (long)(d0 + i * 16 + r16) * L_ + ks * 32 + q8);
#pragma unroll
            for (int j = 0; j < 8; j++) {
                float f = bf2f(raw[j]) * wv[j];
                raw[j] = (short)(__float_as_uint(f) >> 16);
            }
            af[i] = raw;
        }
#pragma unroll
        for (int j = 0; j < 4; j++)
            bq[j] = *(const short8*)(bb + (long)(n0 + j * 16 + r16) * L_ + ks * 32 + q8);
#pragma unroll
        for (int i = 0; i < 4; i++)
#pragma unroll
            for (int j = 0; j < 4; j++)
                acc[i][j] = __builtin_amdgcn_mfma_f32_16x16x32_bf16(af[i], bq[j], acc[i][j], 0, 0, 0);
    }
    bf16* up = U + (((long)c * B_ + b) * H_ + h) * 16384;
#pragma unroll
    for (int i = 0; i < 4; i++)
#pragma unroll
        for (int j = 0; j < 4; j++)
#pragma unroll
            for (int r = 0; r < 4; r++)
                up[(d0 + i * 16 + rq + r) * 128 + (n0 + j * 16 + r16)] = __float2bfloat16(acc[i][j][r]);
}

// h recurrence -> bf16 states entering each chunk (vectorized x8)
__global__ void k_ssd2(const bf16* __restrict__ U, const float* __restrict__ cumlast,
                       bf16* __restrict__ hst)
{
    const long tot = (long)B_ * H_ * HD_ * N_;
    long idx = ((long)blockIdx.x * 256 + threadIdx.x) * 8;
    if (idx >= tot) return;
    int bh = (int)(idx >> 14);
    int b = bh >> 4, h = bh & 15;
    float hv[8];
#pragma unroll
    for (int j = 0; j < 8; j++) hv[j] = 0.f;
    for (int c = 0; c < NC_; c++) {
        float ef = __expf(cumlast[b * 256 + c * 16 + h]);
        short8 u = *(const short8*)(U + c * tot + idx);
        short8 o;
#pragma unroll
        for (int j = 0; j < 8; j++) {
            o[j] = f2bf(hv[j]);
            hv[j] = ef * hv[j] + bf2f(u[j]);
        }
        *(short8*)(hst + c * tot + idx) = o;
    }
}

// Fused intra+inter SSD output, flash-style MFMA. Writes gated bf16 yg.
__global__ __launch_bounds__(256, 2) void k_ssd_y(
    const bf16* __restrict__ bc_b, const bf16* __restrict__ vT,
    const bf16* __restrict__ hst, const float* __restrict__ cum_g,
    const float* __restrict__ Dskip, const bf16* __restrict__ gate_b,
    bf16* __restrict__ yg)
{
    int bid = blockIdx.x;
    int h = bid & 15, c = (bid >> 4) & 15, b = bid >> 8;
    long rowbase = (long)b * L_ + c * CS_;
    int tid = threadIdx.x, lane = tid & 63, wave = tid >> 6;
    int r16 = lane & 15, q8 = (lane >> 4) * 8, rq = (lane >> 4) * 4;
    int wt = (wave >> 1) * 32, wmS = (wave & 1) * 32, wd = (wave & 1) * 64;

    __shared__ float cum_s[256];
    __shared__ __align__(16) bf16 Ss[64][72];

    cum_s[tid] = cum_g[(rowbase + tid) * H_ + h];
    __syncthreads();

    const bf16* Cb  = bc_b + rowbase * 4096 + 2048 + h * 128;
    const bf16* Bb  = bc_b + rowbase * 4096 + h * 128;
    const bf16* vTb = vT + ((long)b * 2048 + h * 128) * L_ + c * 256;
    const bf16* hp  = hst + (((long)c * B_ + b) * H_ + h) * 16384;

    floatx4 zero4 = {0.f, 0.f, 0.f, 0.f};

    for (int tt = 0; tt < 4; tt++) {
        int tbase = tt * 64;
        short8 caf[2][4];
#pragma unroll
        for (int i = 0; i < 2; i++)
#pragma unroll
            for (int ks = 0; ks < 4; ks++)
                caf[i][ks] = *(const short8*)(Cb + (long)(tbase + wt + i * 16 + r16) * 4096 + ks * 32 + q8);

        floatx4 yacc[2][4];
#pragma unroll
        for (int i = 0; i < 2; i++)
#pragma unroll
            for (int j = 0; j < 4; j++) yacc[i][j] = zero4;
#pragma unroll
        for (int ks = 0; ks < 4; ks++)
#pragma unroll
            for (int j = 0; j < 4; j++) {
                short8 hq = *(const short8*)(hp + (long)(wd + j * 16 + r16) * 128 + ks * 32 + q8);
#pragma unroll
                for (int i = 0; i < 2; i++)
                    yacc[i][j] = __builtin_amdgcn_mfma_f32_16x16x32_bf16(caf[i][ks], hq, yacc[i][j], 0, 0, 0);
            }
        float texp[2][4];
#pragma unroll
        for (int i = 0; i < 2; i++)
#pragma unroll
            for (int r = 0; r < 4; r++)
                texp[i][r] = __expf(cum_s[tbase + wt + i * 16 + rq + r]);
#pragma unroll
        for (int i = 0; i < 2; i++)
#pragma unroll
            for (int j = 0; j < 4; j++)
#pragma unroll
                for (int r = 0; r < 4; r++) yacc[i][j][r] *= texp[i][r];

        for (int mt = 0; mt <= tt; mt++) {
            int mbase = mt * 64;
            floatx4 sacc[2][2];
#pragma unroll
            for (int i = 0; i < 2; i++)
#pragma unroll
                for (int j = 0; j < 2; j++) sacc[i][j] = zero4;
#pragma unroll
            for (int ks = 0; ks < 4; ks++) {
                short8 bq[2];
#pragma unroll
                for (int j = 0; j < 2; j++)
                    bq[j] = *(const short8*)(Bb + (long)(mbase + wmS + j * 16 + r16) * 4096 + ks * 32 + q8);
#pragma unroll
                for (int i = 0; i < 2; i++)
#pragma unroll
                    for (int j = 0; j < 2; j++)
                        sacc[i][j] = __builtin_amdgcn_mfma_f32_16x16x32_bf16(caf[i][ks], bq[j], sacc[i][j], 0, 0, 0);
            }
            __syncthreads();
#pragma unroll
            for (int i = 0; i < 2; i++)
#pragma unroll
                for (int r = 0; r < 4; r++) {
                    int trow = wt + i * 16 + rq + r;
                    float ct = cum_s[tbase + trow];
#pragma unroll
                    for (int j = 0; j < 2; j++) {
                        int mcol = mbase + wmS + j * 16 + r16;
                        float val = (mcol <= tbase + trow) ? sacc[i][j][r] * __expf(ct - cum_s[mcol]) : 0.f;
                        Ss[trow][wmS + j * 16 + r16] = __float2bfloat16(val);
                    }
                }
            __syncthreads();
#pragma unroll
            for (int ks = 0; ks < 2; ks++) {
                short8 saf[2];
#pragma unroll
                for (int i = 0; i < 2; i++)
                    saf[i] = *(const short8*)&Ss[wt + i * 16 + r16][ks * 32 + q8];
#pragma unroll
                for (int j = 0; j < 4; j++) {
                    short8 vq = *(const short8*)(vTb + (long)(wd + j * 16 + r16) * L_ + mbase + ks * 32 + q8);
#pragma unroll
                    for (int i = 0; i < 2; i++)
                        yacc[i][j] = __builtin_amdgcn_mfma_f32_16x16x32_bf16(saf[i], vq, yacc[i][j], 0, 0, 0);
                }
            }
        }
#pragma unroll
        for (int i = 0; i < 2; i++)
#pragma unroll
            for (int r = 0; r < 4; r++) {
                int t = tbase + wt + i * 16 + rq + r;
                long grow = (rowbase + t) * 2048 + h * 128;
#pragma unroll
                for (int j = 0; j < 4; j++) {
                    int d = wd + j * 16 + r16;
                    float vv = __bfloat162float(vTb[(long)d * L_ + t]);
                    float y = yacc[i][j][r] + Dskip[h * 128 + d] * vv;
                    float g = __bfloat162float(gate_b[grow + d]);
                    float sg = g / (1.f + __expf(-g));
                    yg[grow + d] = __float2bfloat16(y * sg);
                }
            }
    }
}

// shifted+gw-weighted transpose from bf16 out: dst[d][l] = gw[l%256]*out[l-1][d]
__global__ void k_trans_wkg(const bf16* __restrict__ outg, const float* __restrict__ scr,
                            bf16* __restrict__ dstg)
{
    __shared__ float t[32][33];
    int b = blockIdx.z;
    const bf16* src = outg + (long)b * L_ * D_;
    bf16* dst = dstg + (long)b * D_ * L_;
    int r0 = blockIdx.x * 32, c0 = blockIdx.y * 32;
    int tx = threadIdx.x & 31, ty = threadIdx.x >> 5;
    for (int i = 0; i < 32; i += 8) {
        int rr = r0 + ty + i;
        float g = scr[272 + (rr & 255)];
        t[ty + i][tx] = (rr == 0) ? 0.f : __bfloat162float(src[(long)(rr - 1) * D_ + c0 + tx]) * g;
    }
    __syncthreads();
    for (int i = 0; i < 32; i += 8)
        dst[(long)(c0 + ty + i) * L_ + r0 + tx] = __float2bfloat16(t[tx][ty + i]);
}

// W recurrence, in place, vectorized x8
__global__ void k_m2(bf16* __restrict__ UwW, const float* __restrict__ scr)
{
    const long tot = (long)B_ * D_ * D_;
    long idx = ((long)blockIdx.x * 256 + threadIdx.x) * 8;
    if (idx >= tot) return;
    float gMC = scr[2];
    float w[8];
#pragma unroll
    for (int j = 0; j < 8; j++) w[j] = 0.f;
    for (int c = 0; c < NC_; c++) {
        short8 u = *(const short8*)(UwW + c * tot + idx);
        short8 o;
#pragma unroll
        for (int j = 0; j < 8; j++) {
            o[j] = f2bf(w[j]);
            w[j] = gMC * w[j] + bf2f(u[j]);
        }
        *(short8*)(UwW + c * tot + idx) = o;
    }
}

// ---------------------------------------------------------------------------
// Host side
// ---------------------------------------------------------------------------
static inline int cdiv_i(long a, long b) { return (int)((a + b - 1) / b); }

static void run_gemm(hipStream_t st, int epi, const bf16* A, const bf16* Bt,
                     float* C, bf16* CB, bf16* CB2, bf16* CB3,
                     const float* add0, const float* add1, const bf16* add0b,
                     const float* scr, int M, int N, int K,
                     long lda, long ldb, long ldc, int nbatch, int zinner,
                     long a_zo, long a_zi, long b_zo, long b_zi, long c_zo, long c_zi,
                     int tri = 0, bf16* CB4 = nullptr)
{
    GemmP p;
    p.A = A; p.Bt = Bt; p.C = C; p.CB = CB; p.CB2 = CB2; p.CB3 = CB3; p.CB4 = CB4;
    p.add0 = add0; p.add1 = add1; p.add0b = add0b; p.scr = scr;
    p.lda = lda; p.ldb = ldb; p.ldc = ldc;
    p.M = M; p.N = N; p.K = K; p.zinner = zinner; p.tri = tri;
    p.a_zo = a_zo; p.a_zi = a_zi; p.b_zo = b_zo; p.b_zi = b_zi; p.c_zo = c_zo; p.c_zi = c_zi;
    dim3 g(cdiv_i(N, 128), cdiv_i(M, 128), nbatch);
    dim3 b(256);
    switch (epi) {
        case 0: gemm_bt<0><<<g, b, 0, st>>>(p); break;
        case 2: gemm_bt<2><<<g, b, 0, st>>>(p); break;
        case 3: gemm_bt<3><<<g, b, 0, st>>>(p); break;
        case 4: gemm_bt<4><<<g, b, 0, st>>>(p); break;
        case 6: gemm_bt<6><<<g, b, 0, st>>>(p); break;
        case 7: gemm_bt<7><<<g, b, 0, st>>>(p); break;
        case 8: gemm_bt<8><<<g, b, 0, st>>>(p); break;
        case 9: gemm_bt<9><<<g, b, 0, st>>>(p); break;
    }
}

extern "C" void kernel_launch(void* const* d_in, const int* in_sizes, int n_in,
                              void* d_out, int out_size, void* d_ws, size_t ws_size,
                              hipStream_t stream)
{
    const float* x       = (const float*)d_in[0];
    const float* norm_w  = (const float*)d_in[1];
    const float* w_in    = (const float*)d_in[2];
    const float* conv_w  = (const float*)d_in[3];
    const float* conv_b  = (const float*)d_in[4];
    const float* A_log   = (const float*)d_in[5];
    const float* dt_bias = (const float*)d_in[6];
    const float* D_skip  = (const float*)d_in[7];
    const float* w_out   = (const float*)d_in[8];
    const float* w_write = (const float*)d_in[9];
    const float* w_read  = (const float*)d_in[10];
    const float* decay   = (const float*)d_in[11];
    float* outp = (float*)d_out;

    // ---- workspace layout (lifetime overlays) ----
    const size_t SZ_SCR  = 4096;
    const size_t SZ_DT   = (size_t)B_ * L_ * H_ * 4;
    const size_t SZ_CUML = 2048;
    const size_t SZ_WOUT = (size_t)D_ * DI_ * 2;
    const size_t SZ_WSML = (size_t)D_ * D_ * 2;
    const size_t SZ_R1   = (size_t)B_ * L_ * 2048 * 2;
    const size_t SZ_R2   = SZ_R1;
    const size_t SZ_R3   = (size_t)B_ * L_ * 4096 * 2;
    const size_t SZ_R4   = (size_t)B_ * L_ * D_ * 2 + (size_t)PROJ_ * D_ * 2;
    const size_t SZ_R5   = (size_t)B_ * L_ * 2048 * 4;

    size_t o = 0;
    auto take = [&](size_t sz) { size_t r = o; o += (sz + 255) & ~(size_t)255; return r; };
    const size_t O_SCR = take(SZ_SCR);
    const size_t O_DT  = take(SZ_DT);
    const size_t O_LD  = take(SZ_DT);
    const size_t O_CUM = take(SZ_DT);
    const size_t O_CL  = take(SZ_CUML);
    const size_t O_WO  = take(SZ_WOUT);
    const size_t O_WW  = take(SZ_WSML);
    const size_t O_WR  = take(SZ_WSML);
    const size_t O_R1  = take(SZ_R1);
    const size_t O_R2  = take(SZ_R2);
    const size_t O_R3  = take(SZ_R3);
    const size_t O_R4  = take(SZ_R4);
    const size_t O_R5  = take(SZ_R5);
    const size_t NEED = o;
    if (ws_size < NEED) return;
    (void)O_LD;

    char* ws = (char*)d_ws;
    float* scr     = (float*)(ws + O_SCR);
    float* dt_raw  = (float*)(ws + O_DT);
    float* cum_g   = (float*)(ws + O_CUM);
    float* cumlast = (float*)(ws + O_CL);
    bf16*  w_out_b   = (bf16*)(ws + O_WO);
    bf16*  w_write_b = (bf16*)(ws + O_WW);
    bf16*  w_read_b  = (bf16*)(ws + O_WR);

    bf16*  valT    = (bf16*)(ws + O_R1);   // transposed val (proj bounce)
    bf16*  yg_b    = (bf16*)(ws + O_R1);
    bf16*  hst_b   = (bf16*)(ws + O_R1 + (size_t)B_ * L_ * D_ * 2);
    bf16*  Sm_b    = (bf16*)(ws + O_R1);
    bf16*  intra_b = (bf16*)(ws + O_R1 + (size_t)NC_ * B_ * MC_ * MC_ * 2);
    bf16*  gate_b  = (bf16*)(ws + O_R2);
    bf16*  out_b   = (bf16*)(ws + O_R2);
    bf16*  wk_b    = (bf16*)(ws + O_R2 + (size_t)B_ * L_ * D_ * 2);
    bf16*  reads_b = wk_b;
    bf16*  bc_b    = (bf16*)(ws + O_R3);
    bf16*  UwW     = (bf16*)(ws + O_R3);
    bf16*  xn_b    = (bf16*)(ws + O_R4);
    bf16*  w_in_b  = (bf16*)(ws + O_R4 + (size_t)B_ * L_ * D_ * 2);
    bf16*  U_ssd   = (bf16*)(ws + O_R4);
    bf16*  vT_g    = (bf16*)(ws + O_R5);
    bf16*  BT_g    = (bf16*)(ws + O_R5 + (size_t)B_ * L_ * 2048 * 2);
    bf16*  vTm     = (bf16*)(ws + O_R5 + (size_t)B_ * L_ * D_ * 4);
    bf16*  wkgT    = (bf16*)(ws + O_R5 + (size_t)B_ * L_ * D_ * 4 + (size_t)B_ * L_ * D_ * 2);

    k_gamma<<<1, 256, 0, stream>>>(decay, scr);
    {
        long n0 = (long)PROJ_ * D_ / 4, n1 = (long)D_ * DI_ / 4;
        long n2 = (long)D_ * D_ / 4,   n3 = n2;
        k_f2ball<<<cdiv_i(n0 + n1 + n2 + n3, 256), 256, 0, stream>>>(
            w_in, w_in_b, n0, w_out, w_out_b, n1, w_write, w_write_b, n2, w_read, w_read_b, n3);
    }
    k_rmsnorm<<<B_ * L_, 256, 0, stream>>>(x, norm_w, xn_b);
    // proj: valT (bounced) + gate + bc + BT (bounced) + dt
    run_gemm(stream, 2, xn_b, w_in_b, dt_raw, valT, gate_b, bc_b, nullptr, nullptr, nullptr, nullptr,
             B_ * L_, PROJ_, D_, D_, D_, 0, 1, 1, 0, 0, 0, 0, 0, 0, 0, BT_g);
    k_cum<<<B_ * NC_ * H_, 256, 0, stream>>>(dt_raw, dt_bias, A_log, cum_g, cumlast);
    // conv+silu on transposed layout
    k_vtc2<<<dim3(L_ / 2048, B_ * DI_), 256, 0, stream>>>(valT, conv_w, conv_b, vT_g);
    // SSD
    k_ssd_u2<<<B_ * NC_ * H_, 256, 0, stream>>>(vT_g, BT_g, cum_g, cumlast, U_ssd);
    k_ssd2<<<cdiv_i((long)B_ * H_ * HD_ * N_ / 8, 256), 256, 0, stream>>>(U_ssd, cumlast, hst_b);
    k_ssd_y<<<B_ * NC_ * H_, 256, 0, stream>>>(bc_b, vT_g, hst_b, cum_g, D_skip, gate_b, yg_b);
    // out projection (bf16 + fused shift into wk)
    run_gemm(stream, 8, yg_b, w_out_b, nullptr, out_b, wk_b, nullptr, nullptr, nullptr, nullptr, nullptr,
             B_ * L_, D_, DI_, DI_, DI_, D_, 1, 1, 0, 0, 0, 0, 0, 0);
    // memory scan: write-GEMM emits vTm transposed directly
    run_gemm(stream, 9, out_b, w_write_b, nullptr, vTm, nullptr, nullptr, nullptr, nullptr, nullptr, nullptr,
             B_ * L_, D_, D_, D_, D_, D_, 1, 1, 0, 0, 0, 0, 0, 0);
    k_trans_wkg<<<dim3(L_ / 32, D_ / 32, B_), 256, 0, stream>>>(out_b, scr, wkgT);
    run_gemm(stream, 6, vTm, wkgT, nullptr, UwW, nullptr, nullptr, nullptr, nullptr, nullptr, nullptr,
             D_, D_, MC_, L_, L_, D_, B_ * NC_, NC_,
             (long)D_ * L_, MC_, (long)D_ * L_, MC_, (long)D_ * D_, (long)B_ * D_ * D_);
    k_m2<<<cdiv_i((long)B_ * D_ * D_ / 8, 256), 256, 0, stream>>>(UwW, scr);
    run_gemm(stream, 3, out_b, wk_b, nullptr, Sm_b, nullptr, nullptr, nullptr, nullptr, nullptr, scr,
             MC_, MC_, D_, D_, D_, MC_, B_ * NC_, NC_,
             (long)L_ * D_, (long)MC_ * D_, (long)L_ * D_, (long)MC_ * D_,
             (long)MC_ * MC_, (long)B_ * MC_ * MC_, 1);
    run_gemm(stream, 6, Sm_b, vTm, nullptr, intra_b, nullptr, nullptr, nullptr, nullptr, nullptr, nullptr,
             MC_, D_, MC_, MC_, L_, D_, B_ * NC_, NC_,
             (long)MC_ * MC_, (long)B_ * MC_ * MC_, (long)D_ * L_, MC_,
             (long)L_ * D_, (long)MC_ * D_, 2);
    run_gemm(stream, 4, out_b, UwW, nullptr, reads_b, nullptr, nullptr, nullptr, nullptr, intra_b, scr,
             MC_, D_, D_, D_, D_, D_, B_ * NC_, NC_,
             (long)L_ * D_, (long)MC_ * D_, (long)D_ * D_, (long)B_ * D_ * D_,
             (long)L_ * D_, (long)MC_ * D_);
    // final: d_out = x + out + 0.5 * reads @ w_read^T
    run_gemm(stream, 7, reads_b, w_read_b, outp, nullptr, nullptr, nullptr, x, nullptr, out_b, nullptr,
             B_ * L_, D_, D_, D_, D_, D_, 1, 1, 0, 0, 0, 0, 0, 0);
}